// Round 20
// baseline (1312.365 us; speedup 1.0000x reference)
//
#include <hip/hip_runtime.h>
#include <hip/hip_bf16.h>

#define AS1 __attribute__((address_space(1)))
#define AS3 __attribute__((address_space(3)))

typedef __bf16 bf16x8 __attribute__((ext_vector_type(8)));
typedef float f32x4 __attribute__((ext_vector_type(4)));

static constexpr int C_DIM = 1024;
static constexpr int H_DIM = 4096;
static constexpr int NTOK  = 8192;   // 4*2048
static constexpr int NR    = 7;      // routed experts
static constexpr int NSLOT = 17408;  // gathered-slot capacity / partial stride
static constexpr int MAXT  = 136;    // launch y-tiles for routed (128-granular)
static constexpr size_t WSZ = (size_t)C_DIM * H_DIM;  // elems per expert weight

static __device__ __forceinline__ unsigned short f2bf(float f) {
  __hip_bfloat16 h = __float2bfloat16(f);
  return *reinterpret_cast<unsigned short*>(&h);
}
static __device__ __forceinline__ float bf2f(unsigned short u) {
  unsigned int v = ((unsigned int)u) << 16;
  return *reinterpret_cast<float*>(&v);
}

// tanh-form GELU: x*sigmoid(2a(x+bx^3)); |err| ~3e-4 << bf16 quantization of Y
static __device__ __forceinline__ float gelu_fast(float v) {
  const float u2 = -2.0f * v * (0.7978845608f + 0.0356774081f * v * v);
  return v * __builtin_amdgcn_rcpf(1.0f + __expf(u2));
}

static __device__ __forceinline__ void gload16(const void* g, void* lds) {
  __builtin_amdgcn_global_load_lds((const AS1 void*)g, (AS3 void*)lds, 16, 0, 0);
}

// Grouped-XCD tile decode (bijective): XCD owns gy/8 consecutive m-tiles; within
// an XCD, groups of GM m-tiles iterate n-major (L2 panel locality).  gy%8==0.
static __device__ __forceinline__ void tile_decode(int f, int gx, int gy,
                                                   int& ty, int& bx) {
  const int myc = gy >> 3;
  const int xcd = f & 7;
  const int r = f >> 3;
  const int GM = 8;
  const int nig = GM * gx;
  const int grp = r / nig;
  const int first = grp * GM;
  const int gsz = min(GM, myc - first);
  const int rin = r - grp * nig;
  ty = xcd * myc + first + rin % gsz;
  bx = rin / gsz;
}

// ---------------- cast x (fp32 -> bf16) ----------------
__global__ __launch_bounds__(256) void cast_x_kernel(const float* __restrict__ x,
                                                     unsigned short* __restrict__ xb) {
  size_t i = ((size_t)blockIdx.x * blockDim.x + threadIdx.x) * 4;
  float4 v = *(const float4*)(x + i);
  ushort4 o;
  o.x = f2bf(v.x); o.y = f2bf(v.y); o.z = f2bf(v.z); o.w = f2bf(v.w);
  *(ushort4*)(xb + i) = o;
}

// ---------------- init: zero idx / cnt / cursor ----------------
__global__ __launch_bounds__(256) void init_kernel(int* __restrict__ idx, int* __restrict__ cnt,
                                                   int* __restrict__ cursor) {
  int i = blockIdx.x * 256 + threadIdx.x;
  if (i < NSLOT) idx[i] = 0;
  if (blockIdx.x == 0 && threadIdx.x < 8) { cnt[threadIdx.x] = 0; cursor[threadIdx.x] = 0; }
}

// ---------------- routing: one wave per token; writes cw + counts ----------------
__global__ __launch_bounds__(256) void routing_kernel(const float* __restrict__ x,
                                                      const float* __restrict__ gw,
                                                      const float* __restrict__ bias,
                                                      float* __restrict__ cw,
                                                      int* __restrict__ cnt) {
  int wid = (int)((blockIdx.x * (size_t)blockDim.x + threadIdx.x) >> 6);
  int lane = threadIdx.x & 63;
  if (wid >= NTOK) return;
  const float* xt = x + (size_t)wid * C_DIM;
  float p[NR] = {0.f, 0.f, 0.f, 0.f, 0.f, 0.f, 0.f};
  for (int i = lane; i < C_DIM; i += 64) {
    float xv = xt[i];
#pragma unroll
    for (int e = 0; e < NR; ++e) p[e] += xv * gw[e * C_DIM + i];
  }
#pragma unroll
  for (int e = 0; e < NR; ++e) {
#pragma unroll
    for (int off = 32; off; off >>= 1) p[e] += __shfl_down(p[e], off);
  }
  if (lane == 0) {
    float m = p[0];
#pragma unroll
    for (int e = 1; e < NR; ++e) m = fmaxf(m, p[e]);
    float pr[NR], s = 0.f;
#pragma unroll
    for (int e = 0; e < NR; ++e) { pr[e] = __expf(p[e] - m); s += pr[e]; }
    float inv = 1.0f / s;
#pragma unroll
    for (int e = 0; e < NR; ++e) pr[e] *= inv;
    float sel[NR];
#pragma unroll
    for (int e = 0; e < NR; ++e) sel[e] = p[e] + bias[e];
    int i1 = 0;
#pragma unroll
    for (int e = 1; e < NR; ++e) if (sel[e] > sel[i1]) i1 = e;
    int i2 = -1;
#pragma unroll
    for (int e = 0; e < NR; ++e) {
      if (e == i1) continue;
      if (i2 < 0 || sel[e] > sel[i2]) i2 = e;
    }
    float c[NR] = {0.f, 0.f, 0.f, 0.f, 0.f, 0.f, 0.f};
    c[i1] = pr[i1];
    c[i2] += pr[i2];
#pragma unroll
    for (int e = 0; e < NR; ++e) cw[(size_t)wid * NR + e] = c[e];
    atomicAdd(&cnt[i1], 1);
    atomicAdd(&cnt[i2], 1);
  }
}

// ---------------- scan: offsets + compact 128-granular tile map ----------------
__global__ void scan_kernel(const int* __restrict__ cnt, int* __restrict__ offs,
                            int* __restrict__ tmap, int* __restrict__ ntiles) {
  int o = 0, nt = 0;
  for (int e = 0; e < NR; ++e) {
    offs[e] = o;
    int n = (cnt[e] + 127) & ~127;
    o += n;
    for (int tm = 0; tm < n; tm += 128) tmap[nt++] = (e << 16) | tm;
  }
  *ntiles = nt;
}

// ---------------- place: fill gathered index lists + per-token slot/weight ----------------
__global__ __launch_bounds__(256) void place_kernel(const float* __restrict__ cw,
                                                    const int* __restrict__ offs,
                                                    int* __restrict__ cursor,
                                                    int* __restrict__ idx,
                                                    int* __restrict__ tok2slot,
                                                    float* __restrict__ tok2w) {
  int t = blockIdx.x * 256 + threadIdx.x;
  if (t >= NTOK) return;
  int k = 0;
#pragma unroll
  for (int e = 0; e < NR; ++e) {
    float w = cw[(size_t)t * NR + e];
    if (w > 0.f) {
      int p = atomicAdd(&cursor[e], 1);
      int slot = offs[e] + p;
      idx[slot] = t;
      tok2slot[t * 2 + k] = slot;
      tok2w[t * 2 + k] = w;
      ++k;
    }
  }
}

// ---------------- transpose + cast all 8 experts: fp32 [R][S] -> bf16 [S][R] ----------------
__global__ void transpose_cast_all(const float* __restrict__ shared_w,
                                   const float* __restrict__ routed_w,
                                   unsigned short* __restrict__ out, int R, int S) {
  int e = blockIdx.z;
  const float* in = (e == 0) ? shared_w : routed_w + (size_t)(e - 1) * R * S;
  unsigned short* o = out + (size_t)e * R * S;
  __shared__ float t[32][33];
  int bx = blockIdx.x * 32;  // S
  int by = blockIdx.y * 32;  // R
  int tx = threadIdx.x, ty = threadIdx.y;  // (32, 8)
#pragma unroll
  for (int i = 0; i < 32; i += 8)
    t[ty + i][tx] = in[(size_t)(by + ty + i) * S + bx + tx];
  __syncthreads();
#pragma unroll
  for (int i = 0; i < 32; i += 8)
    o[(size_t)(bx + ty + i) * R + by + tx] = f2bf(t[tx][ty + i]);
}

// ====== fc GEMM: 128^2, BK=64, 2-buffer counted-vmcnt (barrier-halving test) ======
// LDS per matrix per buf: [kg=8][row=128][8e] = 16 KB; total 64 KB -> 2 blocks/CU.
// Per iter: issue next tile into buf^1 (8 gloads) -> vmcnt(8) -> barrier ->
// 16 ds_read + 32 MFMA -> barrier -> flip.  vmcnt never 0 mid-loop.
template <bool GATHER>
__global__ __launch_bounds__(256) void gemm_fc(const unsigned short* __restrict__ A,
                                               const unsigned short* __restrict__ BtAll,
                                               unsigned short* __restrict__ Y,
                                               const int* __restrict__ idx,
                                               const int* __restrict__ offs,
                                               const int* __restrict__ tmap,
                                               const int* __restrict__ ntiles) {
  __shared__ __align__(16) unsigned short As[2][8192];
  __shared__ __align__(16) unsigned short Bs[2][8192];
  const int tid = threadIdx.x;
  const int wave = tid >> 6, lane = tid & 63;
  constexpr int NT = C_DIM / 64;

  int bx, ty;
  {
    const int f = blockIdx.y * gridDim.x + blockIdx.x;
    tile_decode(f, gridDim.x, gridDim.y, ty, bx);
  }

  int m0, n0, base;
  const unsigned short* Bt;
  if (GATHER) {
    if (ty >= *ntiles) return;
    const int packed = tmap[ty];
    const int e = packed >> 16;
    m0 = packed & 0xffff;
    n0 = bx * 128;
    base = offs[e];
    Bt = BtAll + (size_t)(e + 1) * WSZ;
  } else {
    m0 = ty * 128;
    n0 = bx * 128;
    base = 0;
    Bt = BtAll;
  }

  // staging: thread covers row (wave&1)*64+lane at kg = (wave>>1)+2i, i=0..3
  const int srow = (wave & 1) * 64 + lane;
  const int kgb = wave >> 1;                     // 0..1
  const size_t rowA = GATHER ? (size_t)idx[base + m0 + srow] : (size_t)(m0 + srow);
  const unsigned short* gA = A + rowA * C_DIM + kgb * 8;
  const unsigned short* gB = Bt + (size_t)(n0 + srow) * C_DIM + kgb * 8;
  // wave-uniform LDS chunk-run bases (shorts) for i=0..3: ((kgb+2i)*1024 + (wave&1)*512)
  const int dbase = kgb * 1024 + (wave & 1) * 512;

  const int wr = wave >> 1, wc = wave & 1;       // 2x2 wave grid, each 64x64
  const int fr = lane & 15, fq = lane >> 4;
  f32x4 acc[4][4] = {};

  asm volatile("s_waitcnt vmcnt(0)" ::: "memory");  // idx loads retired
  // prologue: tile 0 -> buf 0 (4 chunks per matrix per thread)
#pragma unroll
  for (int i = 0; i < 4; ++i) {
    gload16(gA + i * 16, &As[0][dbase + i * 2048]);
    gload16(gB + i * 16, &Bs[0][dbase + i * 2048]);
  }

  int rb = 0;
  for (int t = 0; t < NT; ++t) {
    if (t + 1 < NT) {
      const int wb = rb ^ 1;        // freed by previous iteration's trailing barrier
      const int nk = (t + 1) * 64;
#pragma unroll
      for (int i = 0; i < 4; ++i) {
        gload16(gA + nk + i * 16, &As[wb][dbase + i * 2048]);
        gload16(gB + nk + i * 16, &Bs[wb][dbase + i * 2048]);
      }
      asm volatile("s_waitcnt vmcnt(8)" ::: "memory");  // own tile-t loads landed
    } else {
      asm volatile("s_waitcnt vmcnt(0)" ::: "memory");
    }
    __builtin_amdgcn_s_barrier();   // all waves' tile-t data in LDS
    bf16x8 af[4][2], bfr[4][2];
#pragma unroll
    for (int m = 0; m < 4; ++m)
#pragma unroll
      for (int ks = 0; ks < 2; ++ks)
        af[m][ks] = *(const bf16x8*)&As[rb][(ks * 4 + fq) * 1024 + (wr * 64 + m * 16 + fr) * 8];
#pragma unroll
    for (int n = 0; n < 4; ++n)
#pragma unroll
      for (int ks = 0; ks < 2; ++ks)
        bfr[n][ks] = *(const bf16x8*)&Bs[rb][(ks * 4 + fq) * 1024 + (wc * 64 + n * 16 + fr) * 8];
#pragma unroll
    for (int m = 0; m < 4; ++m)
#pragma unroll
      for (int n = 0; n < 4; ++n)
#pragma unroll
        for (int ks = 0; ks < 2; ++ks)
          acc[m][n] = __builtin_amdgcn_mfma_f32_16x16x32_bf16(af[m][ks], bfr[n][ks], acc[m][n], 0, 0, 0);
    __builtin_amdgcn_s_barrier();   // buf rb free for reuse (staged next iter)
    rb ^= 1;
  }

#pragma unroll
  for (int m = 0; m < 4; ++m)
#pragma unroll
    for (int n = 0; n < 4; ++n)
#pragma unroll
      for (int j = 0; j < 4; ++j) {
        const int row = m0 + wr * 64 + m * 16 + fq * 4 + j;
        const int col = n0 + wc * 64 + n * 16 + fr;
        const float g = gelu_fast(acc[m][n][j]);
        Y[(size_t)(base + row) * H_DIM + col] = f2bf(g);
      }
}

// ---------------- shared proj: 128^2 BK=32 3-buf, direct fp32 store (R19) ----------------
__global__ __launch_bounds__(256) void gemm_proj_shared(const unsigned short* __restrict__ Yg,
                                                        const unsigned short* __restrict__ Bt,
                                                        float* __restrict__ Out) {
  __shared__ __align__(16) unsigned short As[3][4096];
  __shared__ __align__(16) unsigned short Bs[3][4096];
  const int tid = threadIdx.x;
  const int wave = tid >> 6, lane = tid & 63;
  constexpr int NT = H_DIM / 32;

  int bx, ty;
  {
    const int f = blockIdx.y * gridDim.x + blockIdx.x;
    tile_decode(f, gridDim.x, gridDim.y, ty, bx);
  }
  const int m0 = ty * 128;
  const int n0 = bx * 128;

  const int q0 = wave * 128 + lane, q1 = q0 + 64;
  const int kg0 = q0 >> 7, r0 = q0 & 127;
  const int kg1 = q1 >> 7, r1 = q1 & 127;
  const unsigned short* gA0 = Yg + (size_t)(m0 + r0) * H_DIM + kg0 * 8;
  const unsigned short* gA1 = Yg + (size_t)(m0 + r1) * H_DIM + kg1 * 8;
  const unsigned short* gB0 = Bt + (size_t)(n0 + r0) * H_DIM + kg0 * 8;
  const unsigned short* gB1 = Bt + (size_t)(n0 + r1) * H_DIM + kg1 * 8;
  const int c0 = (wave * 2 + 0) * 512, c1 = (wave * 2 + 1) * 512;

  const int wr = wave >> 1, wc = wave & 1;
  const int fr = lane & 15, fq = lane >> 4;
  f32x4 acc[4][4] = {};

  gload16(gA0, &As[0][c0]); gload16(gA1, &As[0][c1]);
  gload16(gB0, &Bs[0][c0]); gload16(gB1, &Bs[0][c1]);
  gload16(gA0 + 32, &As[1][c0]); gload16(gA1 + 32, &As[1][c1]);
  gload16(gB0 + 32, &Bs[1][c0]); gload16(gB1 + 32, &Bs[1][c1]);

  int rb = 0;
  for (int t = 0; t < NT; ++t) {
    if (t + 2 < NT) {
      const int wb = (rb >= 1) ? rb - 1 : 2;
      const int nk = (t + 2) * 32;
      gload16(gA0 + nk, &As[wb][c0]); gload16(gA1 + nk, &As[wb][c1]);
      gload16(gB0 + nk, &Bs[wb][c0]); gload16(gB1 + nk, &Bs[wb][c1]);
      asm volatile("s_waitcnt vmcnt(8)" ::: "memory");
    } else if (t + 1 < NT) {
      asm volatile("s_waitcnt vmcnt(4)" ::: "memory");
    } else {
      asm volatile("s_waitcnt vmcnt(0)" ::: "memory");
    }
    __builtin_amdgcn_s_barrier();
    bf16x8 af[4], bfr[4];
#pragma unroll
    for (int m = 0; m < 4; ++m)
      af[m] = *(const bf16x8*)&As[rb][fq * 1024 + (wr * 64 + m * 16 + fr) * 8];
#pragma unroll
    for (int n = 0; n < 4; ++n)
      bfr[n] = *(const bf16x8*)&Bs[rb][fq * 1024 + (wc * 64 + n * 16 + fr) * 8];
#pragma unroll
    for (int m = 0; m < 4; ++m)
#pragma unroll
      for (int n = 0; n < 4; ++n)
        acc[m][n] = __builtin_amdgcn_mfma_f32_16x16x32_bf16(af[m], bfr[n], acc[m][n], 0, 0, 0);
    __builtin_amdgcn_s_barrier();
    rb = (rb == 2) ? 0 : rb + 1;
  }

#pragma unroll
  for (int m = 0; m < 4; ++m)
#pragma unroll
    for (int n = 0; n < 4; ++n)
#pragma unroll
      for (int j = 0; j < 4; ++j) {
        const int p = wr * 64 + m * 16 + fq * 4 + j;
        const int col = n0 + wc * 64 + n * 16 + fr;
        Out[(size_t)(m0 + p) * C_DIM + col] = acc[m][n][j];
      }
}

// ------- routed proj: split-K=2, bf16 partials to Pb[z][slot][C] (nt store, R19) -------
__global__ __launch_bounds__(256) void gemm_proj_routed(const unsigned short* __restrict__ Yg,
                                                        const unsigned short* __restrict__ BtAll,
                                                        unsigned short* __restrict__ Pb,
                                                        const int* __restrict__ offs,
                                                        const int* __restrict__ tmap,
                                                        const int* __restrict__ ntiles) {
  __shared__ __align__(16) unsigned short As[3][4096];
  __shared__ __align__(16) unsigned short Bs[3][4096];
  const int tid = threadIdx.x;
  const int wave = tid >> 6, lane = tid & 63;
  constexpr int KSEG = H_DIM / 2;
  constexpr int NT = KSEG / 32;
  const int kbase = blockIdx.z * KSEG;

  int bx, ty;
  {
    const int f = blockIdx.y * gridDim.x + blockIdx.x;
    tile_decode(f, gridDim.x, gridDim.y, ty, bx);
  }

  if (ty >= *ntiles) return;
  const int packed = tmap[ty];
  const int e = packed >> 16;
  const int m0 = packed & 0xffff;
  const int n0 = bx * 128;
  const int base = offs[e];
  const unsigned short* Bt = BtAll + (size_t)(e + 1) * WSZ;

  const int q0 = wave * 128 + lane, q1 = q0 + 64;
  const int kg0 = q0 >> 7, r0 = q0 & 127;
  const int kg1 = q1 >> 7, r1 = q1 & 127;
  const unsigned short* gA0 = Yg + (size_t)(base + m0 + r0) * H_DIM + kbase + kg0 * 8;
  const unsigned short* gA1 = Yg + (size_t)(base + m0 + r1) * H_DIM + kbase + kg1 * 8;
  const unsigned short* gB0 = Bt + (size_t)(n0 + r0) * H_DIM + kbase + kg0 * 8;
  const unsigned short* gB1 = Bt + (size_t)(n0 + r1) * H_DIM + kbase + kg1 * 8;
  const int c0 = (wave * 2 + 0) * 512, c1 = (wave * 2 + 1) * 512;

  const int wr = wave >> 1, wc = wave & 1;
  const int fr = lane & 15, fq = lane >> 4;
  f32x4 acc[4][4] = {};

  gload16(gA0, &As[0][c0]); gload16(gA1, &As[0][c1]);
  gload16(gB0, &Bs[0][c0]); gload16(gB1, &Bs[0][c1]);
  gload16(gA0 + 32, &As[1][c0]); gload16(gA1 + 32, &As[1][c1]);
  gload16(gB0 + 32, &Bs[1][c0]); gload16(gB1 + 32, &Bs[1][c1]);

  int rb = 0;
  for (int t = 0; t < NT; ++t) {
    if (t + 2 < NT) {
      const int wb = (rb >= 1) ? rb - 1 : 2;
      const int nk = (t + 2) * 32;
      gload16(gA0 + nk, &As[wb][c0]); gload16(gA1 + nk, &As[wb][c1]);
      gload16(gB0 + nk, &Bs[wb][c0]); gload16(gB1 + nk, &Bs[wb][c1]);
      asm volatile("s_waitcnt vmcnt(8)" ::: "memory");
    } else if (t + 1 < NT) {
      asm volatile("s_waitcnt vmcnt(4)" ::: "memory");
    } else {
      asm volatile("s_waitcnt vmcnt(0)" ::: "memory");
    }
    __builtin_amdgcn_s_barrier();
    bf16x8 af[4], bfr[4];
#pragma unroll
    for (int m = 0; m < 4; ++m)
      af[m] = *(const bf16x8*)&As[rb][fq * 1024 + (wr * 64 + m * 16 + fr) * 8];
#pragma unroll
    for (int n = 0; n < 4; ++n)
      bfr[n] = *(const bf16x8*)&Bs[rb][fq * 1024 + (wc * 64 + n * 16 + fr) * 8];
#pragma unroll
    for (int m = 0; m < 4; ++m)
#pragma unroll
      for (int n = 0; n < 4; ++n)
        acc[m][n] = __builtin_amdgcn_mfma_f32_16x16x32_bf16(af[m], bfr[n], acc[m][n], 0, 0, 0);
    __builtin_amdgcn_s_barrier();
    rb = (rb == 2) ? 0 : rb + 1;
  }

#pragma unroll
  for (int m = 0; m < 4; ++m)
#pragma unroll
    for (int n = 0; n < 4; ++n)
#pragma unroll
      for (int j = 0; j < 4; ++j) {
        const int p = wr * 64 + m * 16 + fq * 4 + j;
        const int col = n0 + wc * 64 + n * 16 + fr;
        __builtin_nontemporal_store(
            f2bf(acc[m][n][j]),
            &Pb[((size_t)blockIdx.z * NSLOT + base + m0 + p) * C_DIM + col]);
      }
}

// ---- combine: out[t] += w0*(P0[s0]+P1[s0]) + w1*(P0[s1]+P1[s1]), P bf16 ----
__global__ __launch_bounds__(256) void combine_kernel(const unsigned short* __restrict__ P,
                                                      const int* __restrict__ tok2slot,
                                                      const float* __restrict__ tok2w,
                                                      float* __restrict__ out) {
  const int t = blockIdx.x;
  const int c = threadIdx.x * 4;
  const int s0 = tok2slot[t * 2], s1 = tok2slot[t * 2 + 1];
  const float w0 = tok2w[t * 2], w1 = tok2w[t * 2 + 1];
  const ushort4 a0 = *(const ushort4*)&P[((size_t)0 * NSLOT + s0) * C_DIM + c];
  const ushort4 a1 = *(const ushort4*)&P[((size_t)1 * NSLOT + s0) * C_DIM + c];
  const ushort4 b0 = *(const ushort4*)&P[((size_t)0 * NSLOT + s1) * C_DIM + c];
  const ushort4 b1 = *(const ushort4*)&P[((size_t)1 * NSLOT + s1) * C_DIM + c];
  float4 o = *(float4*)&out[(size_t)t * C_DIM + c];
  o.x += w0 * (bf2f(a0.x) + bf2f(a1.x)) + w1 * (bf2f(b0.x) + bf2f(b1.x));
  o.y += w0 * (bf2f(a0.y) + bf2f(a1.y)) + w1 * (bf2f(b0.y) + bf2f(b1.y));
  o.z += w0 * (bf2f(a0.z) + bf2f(a1.z)) + w1 * (bf2f(b0.z) + bf2f(b1.z));
  o.w += w0 * (bf2f(a0.w) + bf2f(a1.w)) + w1 * (bf2f(b0.w) + bf2f(b1.w));
  *(float4*)&out[(size_t)t * C_DIM + c] = o;
}

extern "C" void kernel_launch(void* const* d_in, const int* in_sizes, int n_in,
                              void* d_out, int out_size, void* d_ws, size_t ws_size,
                              hipStream_t stream) {
  const float* x            = (const float*)d_in[0];
  const float* gate_w       = (const float*)d_in[1];
  const float* lb_bias      = (const float*)d_in[2];
  const float* shared_wfc   = (const float*)d_in[3];
  const float* shared_wproj = (const float*)d_in[4];
  const float* routed_wfc   = (const float*)d_in[5];
  const float* routed_wproj = (const float*)d_in[6];
  float* out = (float*)d_out;

  char* ws = (char*)d_ws;
  unsigned short* xb     = (unsigned short*)(ws);                 // 16 MiB (dead after fcs)
  unsigned short* wfcT   = (unsigned short*)(ws + 16777216);      // 64 MiB (dead after fcs)
  unsigned short* Pb     = (unsigned short*)(ws);                 // 68 MiB partials, OVERLAYS xb+wfcT
  unsigned short* wprojT = (unsigned short*)(ws + 83886080);      // 64 MiB [8][C][H]
  unsigned short* Yg     = (unsigned short*)(ws + 150994944);     // 142.6 MiB [NSLOT][H]
  float*          cw     = (float*)(ws + 293601280);              // 224 KiB
  int*            idx    = (int*)(ws + 293830656);                // 68 KiB (NSLOT)
  int*            cnt    = (int*)(ws + 293901312);
  int*            offs   = (int*)(ws + 293901376);
  int*            cursor = (int*)(ws + 293901440);
  int*            tok2slot = (int*)(ws + 293901504);              // 64 KiB
  float*          tok2w    = (float*)(ws + 293967040);            // 64 KiB
  int*            tmap     = (int*)(ws + 294032576);              // 544 B
  int*            ntiles   = (int*)(ws + 294033152);

  cast_x_kernel<<<NTOK * C_DIM / (256 * 4), 256, 0, stream>>>(x, xb);
  init_kernel<<<(NSLOT + 255) / 256, 256, 0, stream>>>(idx, cnt, cursor);
  routing_kernel<<<NTOK / 4, 256, 0, stream>>>(x, gate_w, lb_bias, cw, cnt);
  scan_kernel<<<1, 1, 0, stream>>>(cnt, offs, tmap, ntiles);
  place_kernel<<<NTOK / 256, 256, 0, stream>>>(cw, offs, cursor, idx, tok2slot, tok2w);

  // all-expert weight transposes (e=0 shared, e=1..7 routed)
  transpose_cast_all<<<dim3(H_DIM / 32, C_DIM / 32, 8), dim3(32, 8), 0, stream>>>(
      shared_wfc, routed_wfc, wfcT, C_DIM, H_DIM);
  transpose_cast_all<<<dim3(C_DIM / 32, H_DIM / 32, 8), dim3(32, 8), 0, stream>>>(
      shared_wproj, routed_wproj, wprojT, H_DIM, C_DIM);

  // shared expert (dense): fc -> Yg[0:8192), proj -> out (direct fp32 store)
  gemm_fc<false><<<dim3(H_DIM / 128, NTOK / 128), 256, 0, stream>>>(
      xb, wfcT, Yg, idx, offs, tmap, ntiles);
  gemm_proj_shared<<<dim3(C_DIM / 128, NTOK / 128), 256, 0, stream>>>(Yg, wprojT, out);

  // routed experts (gathered top-2): grouped-XCD tile grids
  gemm_fc<true><<<dim3(H_DIM / 128, MAXT), 256, 0, stream>>>(
      xb, wfcT, Yg, idx, offs, tmap, ntiles);
  gemm_proj_routed<<<dim3(C_DIM / 128, MAXT, 2), 256, 0, stream>>>(
      Yg, wprojT, Pb, offs, tmap, ntiles);

  // out[t] += w0*(P0+P1)[slot0] + w1*(P0+P1)[slot1]
  combine_kernel<<<NTOK, 256, 0, stream>>>(Pb, tok2slot, tok2w, out);
}

// Round 21
// 1224.046 us; speedup vs baseline: 1.0722x; 1.0722x over previous
//
#include <hip/hip_runtime.h>
#include <hip/hip_bf16.h>

#define AS1 __attribute__((address_space(1)))
#define AS3 __attribute__((address_space(3)))

typedef __bf16 bf16x8 __attribute__((ext_vector_type(8)));
typedef float f32x4 __attribute__((ext_vector_type(4)));

static constexpr int C_DIM = 1024;
static constexpr int H_DIM = 4096;
static constexpr int NTOK  = 8192;   // 4*2048
static constexpr int NR    = 7;      // routed experts
static constexpr int NSLOT = 17408;  // gathered-slot capacity / partial stride
static constexpr int MAXT  = 136;    // launch y-tiles for routed (128-granular)
static constexpr size_t WSZ = (size_t)C_DIM * H_DIM;  // elems per expert weight

static __device__ __forceinline__ unsigned short f2bf(float f) {
  __hip_bfloat16 h = __float2bfloat16(f);
  return *reinterpret_cast<unsigned short*>(&h);
}
static __device__ __forceinline__ float bf2f(unsigned short u) {
  unsigned int v = ((unsigned int)u) << 16;
  return *reinterpret_cast<float*>(&v);
}

// tanh-form GELU: x*sigmoid(2a(x+bx^3)); |err| ~3e-4 << bf16 quantization of Y
static __device__ __forceinline__ float gelu_fast(float v) {
  const float u2 = -2.0f * v * (0.7978845608f + 0.0356774081f * v * v);
  return v * __builtin_amdgcn_rcpf(1.0f + __expf(u2));
}

static __device__ __forceinline__ void gload16(const void* g, void* lds) {
  __builtin_amdgcn_global_load_lds((const AS1 void*)g, (AS3 void*)lds, 16, 0, 0);
}

// Grouped-XCD tile decode (bijective): XCD owns gy/8 consecutive m-tiles; within
// an XCD, groups of GM m-tiles iterate n-major so the ~96 concurrent blocks per
// XCD touch ~GM A-panels + ~(96/GM) B-panels, maximizing L2 panel reuse.
static __device__ __forceinline__ void tile_decode(int f, int gx, int gy,
                                                   int& ty, int& bx) {
  const int myc = gy >> 3;
  const int xcd = f & 7;
  const int r = f >> 3;               // [0, myc*gx)
  const int GM = 8;
  const int nig = GM * gx;
  const int grp = r / nig;
  const int first = grp * GM;
  const int gsz = min(GM, myc - first);
  const int rin = r - grp * nig;
  ty = xcd * myc + first + rin % gsz;
  bx = rin / gsz;
}

// ---------------- cast x (fp32 -> bf16) ----------------
__global__ __launch_bounds__(256) void cast_x_kernel(const float* __restrict__ x,
                                                     unsigned short* __restrict__ xb) {
  size_t i = ((size_t)blockIdx.x * blockDim.x + threadIdx.x) * 4;
  float4 v = *(const float4*)(x + i);
  ushort4 o;
  o.x = f2bf(v.x); o.y = f2bf(v.y); o.z = f2bf(v.z); o.w = f2bf(v.w);
  *(ushort4*)(xb + i) = o;
}

// ---------------- init: zero idx / cnt / cursor ----------------
__global__ __launch_bounds__(256) void init_kernel(int* __restrict__ idx, int* __restrict__ cnt,
                                                   int* __restrict__ cursor) {
  int i = blockIdx.x * 256 + threadIdx.x;
  if (i < NSLOT) idx[i] = 0;
  if (blockIdx.x == 0 && threadIdx.x < 8) { cnt[threadIdx.x] = 0; cursor[threadIdx.x] = 0; }
}

// ---------------- routing: one wave per token; writes cw + counts ----------------
__global__ __launch_bounds__(256) void routing_kernel(const float* __restrict__ x,
                                                      const float* __restrict__ gw,
                                                      const float* __restrict__ bias,
                                                      float* __restrict__ cw,
                                                      int* __restrict__ cnt) {
  int wid = (int)((blockIdx.x * (size_t)blockDim.x + threadIdx.x) >> 6);
  int lane = threadIdx.x & 63;
  if (wid >= NTOK) return;
  const float* xt = x + (size_t)wid * C_DIM;
  float p[NR] = {0.f, 0.f, 0.f, 0.f, 0.f, 0.f, 0.f};
  for (int i = lane; i < C_DIM; i += 64) {
    float xv = xt[i];
#pragma unroll
    for (int e = 0; e < NR; ++e) p[e] += xv * gw[e * C_DIM + i];
  }
#pragma unroll
  for (int e = 0; e < NR; ++e) {
#pragma unroll
    for (int off = 32; off; off >>= 1) p[e] += __shfl_down(p[e], off);
  }
  if (lane == 0) {
    float m = p[0];
#pragma unroll
    for (int e = 1; e < NR; ++e) m = fmaxf(m, p[e]);
    float pr[NR], s = 0.f;
#pragma unroll
    for (int e = 0; e < NR; ++e) { pr[e] = __expf(p[e] - m); s += pr[e]; }
    float inv = 1.0f / s;
#pragma unroll
    for (int e = 0; e < NR; ++e) pr[e] *= inv;
    float sel[NR];
#pragma unroll
    for (int e = 0; e < NR; ++e) sel[e] = p[e] + bias[e];
    int i1 = 0;
#pragma unroll
    for (int e = 1; e < NR; ++e) if (sel[e] > sel[i1]) i1 = e;
    int i2 = -1;
#pragma unroll
    for (int e = 0; e < NR; ++e) {
      if (e == i1) continue;
      if (i2 < 0 || sel[e] > sel[i2]) i2 = e;
    }
    float c[NR] = {0.f, 0.f, 0.f, 0.f, 0.f, 0.f, 0.f};
    c[i1] = pr[i1];
    c[i2] += pr[i2];
#pragma unroll
    for (int e = 0; e < NR; ++e) cw[(size_t)wid * NR + e] = c[e];
    atomicAdd(&cnt[i1], 1);
    atomicAdd(&cnt[i2], 1);
  }
}

// ---------------- scan: offsets + compact 128-granular tile map ----------------
__global__ void scan_kernel(const int* __restrict__ cnt, int* __restrict__ offs,
                            int* __restrict__ tmap, int* __restrict__ ntiles) {
  int o = 0, nt = 0;
  for (int e = 0; e < NR; ++e) {
    offs[e] = o;
    int n = (cnt[e] + 127) & ~127;
    o += n;
    for (int tm = 0; tm < n; tm += 128) tmap[nt++] = (e << 16) | tm;
  }
  *ntiles = nt;
}

// ---------------- place: fill gathered index lists + per-token slot/weight ----------------
__global__ __launch_bounds__(256) void place_kernel(const float* __restrict__ cw,
                                                    const int* __restrict__ offs,
                                                    int* __restrict__ cursor,
                                                    int* __restrict__ idx,
                                                    int* __restrict__ tok2slot,
                                                    float* __restrict__ tok2w) {
  int t = blockIdx.x * 256 + threadIdx.x;
  if (t >= NTOK) return;
  int k = 0;
#pragma unroll
  for (int e = 0; e < NR; ++e) {
    float w = cw[(size_t)t * NR + e];
    if (w > 0.f) {
      int p = atomicAdd(&cursor[e], 1);
      int slot = offs[e] + p;
      idx[slot] = t;
      tok2slot[t * 2 + k] = slot;
      tok2w[t * 2 + k] = w;
      ++k;
    }
  }
}

// ---------------- transpose + cast all 8 experts: fp32 [R][S] -> bf16 [S][R] ----------------
__global__ void transpose_cast_all(const float* __restrict__ shared_w,
                                   const float* __restrict__ routed_w,
                                   unsigned short* __restrict__ out, int R, int S) {
  int e = blockIdx.z;
  const float* in = (e == 0) ? shared_w : routed_w + (size_t)(e - 1) * R * S;
  unsigned short* o = out + (size_t)e * R * S;
  __shared__ float t[32][33];
  int bx = blockIdx.x * 32;  // S
  int by = blockIdx.y * 32;  // R
  int tx = threadIdx.x, ty = threadIdx.y;  // (32, 8)
#pragma unroll
  for (int i = 0; i < 32; i += 8)
    t[ty + i][tx] = in[(size_t)(by + ty + i) * S + bx + tx];
  __syncthreads();
#pragma unroll
  for (int i = 0; i < 32; i += 8)
    o[(size_t)(bx + ty + i) * R + by + tx] = f2bf(t[tx][ty + i]);
}

// ======== GEMM K-loop core: 128^2, 3-buffer depth-2 pipeline, counted vmcnt ========
// (R13/R19 = best measured config, reproduced exactly; vmcnt never drains to 0.)
// Dispatch order matters: shared fc -> shared proj (reads Yg[0:8192)) -> routed fc
// (overwrites those Yg rows with gathered slots) -> routed proj.

// ---------------- fc GEMM: A rows x wfcT -> gelu_fast -> Y (bf16) ----------------
template <bool GATHER>
__global__ __launch_bounds__(256) void gemm_fc(const unsigned short* __restrict__ A,
                                               const unsigned short* __restrict__ BtAll,
                                               unsigned short* __restrict__ Y,
                                               const int* __restrict__ idx,
                                               const int* __restrict__ offs,
                                               const int* __restrict__ tmap,
                                               const int* __restrict__ ntiles) {
  __shared__ __align__(16) unsigned short As[3][4096];
  __shared__ __align__(16) unsigned short Bs[3][4096];
  const int tid = threadIdx.x;
  const int wave = tid >> 6, lane = tid & 63;
  constexpr int NT = C_DIM / 32;

  int bx, ty;
  {
    const int f = blockIdx.y * gridDim.x + blockIdx.x;
    tile_decode(f, gridDim.x, gridDim.y, ty, bx);
  }

  int m0, n0, base;
  const unsigned short* Bt;
  if (GATHER) {
    if (ty >= *ntiles) return;
    const int packed = tmap[ty];
    const int e = packed >> 16;
    m0 = packed & 0xffff;
    n0 = bx * 128;
    base = offs[e];
    Bt = BtAll + (size_t)(e + 1) * WSZ;
  } else {
    m0 = ty * 128;
    n0 = bx * 128;
    base = 0;
    Bt = BtAll;
  }

  const int q0 = wave * 128 + lane, q1 = q0 + 64;
  const int kg0 = q0 >> 7, r0 = q0 & 127;
  const int kg1 = q1 >> 7, r1 = q1 & 127;
  const size_t rowA0 = GATHER ? (size_t)idx[base + m0 + r0] : (size_t)(m0 + r0);
  const size_t rowA1 = GATHER ? (size_t)idx[base + m0 + r1] : (size_t)(m0 + r1);
  const unsigned short* gA0 = A + rowA0 * C_DIM + kg0 * 8;
  const unsigned short* gA1 = A + rowA1 * C_DIM + kg1 * 8;
  const unsigned short* gB0 = Bt + (size_t)(n0 + r0) * C_DIM + kg0 * 8;
  const unsigned short* gB1 = Bt + (size_t)(n0 + r1) * C_DIM + kg1 * 8;
  const int c0 = (wave * 2 + 0) * 512, c1 = (wave * 2 + 1) * 512;

  const int wr = wave >> 1, wc = wave & 1;
  const int fr = lane & 15, fq = lane >> 4;
  f32x4 acc[4][4] = {};

  asm volatile("s_waitcnt vmcnt(0)" ::: "memory");  // idx loads retired
  gload16(gA0, &As[0][c0]); gload16(gA1, &As[0][c1]);
  gload16(gB0, &Bs[0][c0]); gload16(gB1, &Bs[0][c1]);
  gload16(gA0 + 32, &As[1][c0]); gload16(gA1 + 32, &As[1][c1]);
  gload16(gB0 + 32, &Bs[1][c0]); gload16(gB1 + 32, &Bs[1][c1]);

  int rb = 0;
  for (int t = 0; t < NT; ++t) {
    if (t + 2 < NT) {
      const int wb = (rb >= 1) ? rb - 1 : 2;  // (rb+2)%3
      const int nk = (t + 2) * 32;
      gload16(gA0 + nk, &As[wb][c0]); gload16(gA1 + nk, &As[wb][c1]);
      gload16(gB0 + nk, &Bs[wb][c0]); gload16(gB1 + nk, &Bs[wb][c1]);
      asm volatile("s_waitcnt vmcnt(8)" ::: "memory");
    } else if (t + 1 < NT) {
      asm volatile("s_waitcnt vmcnt(4)" ::: "memory");
    } else {
      asm volatile("s_waitcnt vmcnt(0)" ::: "memory");
    }
    __builtin_amdgcn_s_barrier();
    bf16x8 af[4], bfr[4];
#pragma unroll
    for (int m = 0; m < 4; ++m)
      af[m] = *(const bf16x8*)&As[rb][fq * 1024 + (wr * 64 + m * 16 + fr) * 8];
#pragma unroll
    for (int n = 0; n < 4; ++n)
      bfr[n] = *(const bf16x8*)&Bs[rb][fq * 1024 + (wc * 64 + n * 16 + fr) * 8];
#pragma unroll
    for (int m = 0; m < 4; ++m)
#pragma unroll
      for (int n = 0; n < 4; ++n)
        acc[m][n] = __builtin_amdgcn_mfma_f32_16x16x32_bf16(af[m], bfr[n], acc[m][n], 0, 0, 0);
    __builtin_amdgcn_s_barrier();
    rb = (rb == 2) ? 0 : rb + 1;
  }

#pragma unroll
  for (int m = 0; m < 4; ++m)
#pragma unroll
    for (int n = 0; n < 4; ++n)
#pragma unroll
      for (int j = 0; j < 4; ++j) {
        const int row = m0 + wr * 64 + m * 16 + fq * 4 + j;
        const int col = n0 + wc * 64 + n * 16 + fr;
        const float g = gelu_fast(acc[m][n][j]);
        Y[(size_t)(base + row) * H_DIM + col] = f2bf(g);
      }
}

// ---------------- shared proj: direct fp32 store to out ----------------
__global__ __launch_bounds__(256) void gemm_proj_shared(const unsigned short* __restrict__ Yg,
                                                        const unsigned short* __restrict__ Bt,
                                                        float* __restrict__ Out) {
  __shared__ __align__(16) unsigned short As[3][4096];
  __shared__ __align__(16) unsigned short Bs[3][4096];
  const int tid = threadIdx.x;
  const int wave = tid >> 6, lane = tid & 63;
  constexpr int NT = H_DIM / 32;

  int bx, ty;
  {
    const int f = blockIdx.y * gridDim.x + blockIdx.x;
    tile_decode(f, gridDim.x, gridDim.y, ty, bx);
  }
  const int m0 = ty * 128;
  const int n0 = bx * 128;

  const int q0 = wave * 128 + lane, q1 = q0 + 64;
  const int kg0 = q0 >> 7, r0 = q0 & 127;
  const int kg1 = q1 >> 7, r1 = q1 & 127;
  const unsigned short* gA0 = Yg + (size_t)(m0 + r0) * H_DIM + kg0 * 8;
  const unsigned short* gA1 = Yg + (size_t)(m0 + r1) * H_DIM + kg1 * 8;
  const unsigned short* gB0 = Bt + (size_t)(n0 + r0) * H_DIM + kg0 * 8;
  const unsigned short* gB1 = Bt + (size_t)(n0 + r1) * H_DIM + kg1 * 8;
  const int c0 = (wave * 2 + 0) * 512, c1 = (wave * 2 + 1) * 512;

  const int wr = wave >> 1, wc = wave & 1;
  const int fr = lane & 15, fq = lane >> 4;
  f32x4 acc[4][4] = {};

  gload16(gA0, &As[0][c0]); gload16(gA1, &As[0][c1]);
  gload16(gB0, &Bs[0][c0]); gload16(gB1, &Bs[0][c1]);
  gload16(gA0 + 32, &As[1][c0]); gload16(gA1 + 32, &As[1][c1]);
  gload16(gB0 + 32, &Bs[1][c0]); gload16(gB1 + 32, &Bs[1][c1]);

  int rb = 0;
  for (int t = 0; t < NT; ++t) {
    if (t + 2 < NT) {
      const int wb = (rb >= 1) ? rb - 1 : 2;
      const int nk = (t + 2) * 32;
      gload16(gA0 + nk, &As[wb][c0]); gload16(gA1 + nk, &As[wb][c1]);
      gload16(gB0 + nk, &Bs[wb][c0]); gload16(gB1 + nk, &Bs[wb][c1]);
      asm volatile("s_waitcnt vmcnt(8)" ::: "memory");
    } else if (t + 1 < NT) {
      asm volatile("s_waitcnt vmcnt(4)" ::: "memory");
    } else {
      asm volatile("s_waitcnt vmcnt(0)" ::: "memory");
    }
    __builtin_amdgcn_s_barrier();
    bf16x8 af[4], bfr[4];
#pragma unroll
    for (int m = 0; m < 4; ++m)
      af[m] = *(const bf16x8*)&As[rb][fq * 1024 + (wr * 64 + m * 16 + fr) * 8];
#pragma unroll
    for (int n = 0; n < 4; ++n)
      bfr[n] = *(const bf16x8*)&Bs[rb][fq * 1024 + (wc * 64 + n * 16 + fr) * 8];
#pragma unroll
    for (int m = 0; m < 4; ++m)
#pragma unroll
      for (int n = 0; n < 4; ++n)
        acc[m][n] = __builtin_amdgcn_mfma_f32_16x16x32_bf16(af[m], bfr[n], acc[m][n], 0, 0, 0);
    __builtin_amdgcn_s_barrier();
    rb = (rb == 2) ? 0 : rb + 1;
  }

#pragma unroll
  for (int m = 0; m < 4; ++m)
#pragma unroll
    for (int n = 0; n < 4; ++n)
#pragma unroll
      for (int j = 0; j < 4; ++j) {
        const int p = wr * 64 + m * 16 + fq * 4 + j;
        const int col = n0 + wc * 64 + n * 16 + fr;
        Out[(size_t)(m0 + p) * C_DIM + col] = acc[m][n][j];
      }
}

// ------- routed proj: split-K=2, bf16 partials to Pb[z][slot][C] (nt store) -------
__global__ __launch_bounds__(256) void gemm_proj_routed(const unsigned short* __restrict__ Yg,
                                                        const unsigned short* __restrict__ BtAll,
                                                        unsigned short* __restrict__ Pb,
                                                        const int* __restrict__ offs,
                                                        const int* __restrict__ tmap,
                                                        const int* __restrict__ ntiles) {
  __shared__ __align__(16) unsigned short As[3][4096];
  __shared__ __align__(16) unsigned short Bs[3][4096];
  const int tid = threadIdx.x;
  const int wave = tid >> 6, lane = tid & 63;
  constexpr int KSEG = H_DIM / 2;
  constexpr int NT = KSEG / 32;
  const int kbase = blockIdx.z * KSEG;

  int bx, ty;
  {
    const int f = blockIdx.y * gridDim.x + blockIdx.x;
    tile_decode(f, gridDim.x, gridDim.y, ty, bx);
  }

  if (ty >= *ntiles) return;
  const int packed = tmap[ty];
  const int e = packed >> 16;
  const int m0 = packed & 0xffff;
  const int n0 = bx * 128;
  const int base = offs[e];
  const unsigned short* Bt = BtAll + (size_t)(e + 1) * WSZ;

  const int q0 = wave * 128 + lane, q1 = q0 + 64;
  const int kg0 = q0 >> 7, r0 = q0 & 127;
  const int kg1 = q1 >> 7, r1 = q1 & 127;
  const unsigned short* gA0 = Yg + (size_t)(base + m0 + r0) * H_DIM + kbase + kg0 * 8;
  const unsigned short* gA1 = Yg + (size_t)(base + m0 + r1) * H_DIM + kbase + kg1 * 8;
  const unsigned short* gB0 = Bt + (size_t)(n0 + r0) * H_DIM + kbase + kg0 * 8;
  const unsigned short* gB1 = Bt + (size_t)(n0 + r1) * H_DIM + kbase + kg1 * 8;
  const int c0 = (wave * 2 + 0) * 512, c1 = (wave * 2 + 1) * 512;

  const int wr = wave >> 1, wc = wave & 1;
  const int fr = lane & 15, fq = lane >> 4;
  f32x4 acc[4][4] = {};

  gload16(gA0, &As[0][c0]); gload16(gA1, &As[0][c1]);
  gload16(gB0, &Bs[0][c0]); gload16(gB1, &Bs[0][c1]);
  gload16(gA0 + 32, &As[1][c0]); gload16(gA1 + 32, &As[1][c1]);
  gload16(gB0 + 32, &Bs[1][c0]); gload16(gB1 + 32, &Bs[1][c1]);

  int rb = 0;
  for (int t = 0; t < NT; ++t) {
    if (t + 2 < NT) {
      const int wb = (rb >= 1) ? rb - 1 : 2;
      const int nk = (t + 2) * 32;
      gload16(gA0 + nk, &As[wb][c0]); gload16(gA1 + nk, &As[wb][c1]);
      gload16(gB0 + nk, &Bs[wb][c0]); gload16(gB1 + nk, &Bs[wb][c1]);
      asm volatile("s_waitcnt vmcnt(8)" ::: "memory");
    } else if (t + 1 < NT) {
      asm volatile("s_waitcnt vmcnt(4)" ::: "memory");
    } else {
      asm volatile("s_waitcnt vmcnt(0)" ::: "memory");
    }
    __builtin_amdgcn_s_barrier();
    bf16x8 af[4], bfr[4];
#pragma unroll
    for (int m = 0; m < 4; ++m)
      af[m] = *(const bf16x8*)&As[rb][fq * 1024 + (wr * 64 + m * 16 + fr) * 8];
#pragma unroll
    for (int n = 0; n < 4; ++n)
      bfr[n] = *(const bf16x8*)&Bs[rb][fq * 1024 + (wc * 64 + n * 16 + fr) * 8];
#pragma unroll
    for (int m = 0; m < 4; ++m)
#pragma unroll
      for (int n = 0; n < 4; ++n)
        acc[m][n] = __builtin_amdgcn_mfma_f32_16x16x32_bf16(af[m], bfr[n], acc[m][n], 0, 0, 0);
    __builtin_amdgcn_s_barrier();
    rb = (rb == 2) ? 0 : rb + 1;
  }

#pragma unroll
  for (int m = 0; m < 4; ++m)
#pragma unroll
    for (int n = 0; n < 4; ++n)
#pragma unroll
      for (int j = 0; j < 4; ++j) {
        const int p = wr * 64 + m * 16 + fq * 4 + j;
        const int col = n0 + wc * 64 + n * 16 + fr;
        __builtin_nontemporal_store(
            f2bf(acc[m][n][j]),
            &Pb[((size_t)blockIdx.z * NSLOT + base + m0 + p) * C_DIM + col]);
      }
}

// ---- combine: out[t] += w0*(P0[s0]+P1[s0]) + w1*(P0[s1]+P1[s1]), P bf16 ----
__global__ __launch_bounds__(256) void combine_kernel(const unsigned short* __restrict__ P,
                                                      const int* __restrict__ tok2slot,
                                                      const float* __restrict__ tok2w,
                                                      float* __restrict__ out) {
  const int t = blockIdx.x;
  const int c = threadIdx.x * 4;
  const int s0 = tok2slot[t * 2], s1 = tok2slot[t * 2 + 1];
  const float w0 = tok2w[t * 2], w1 = tok2w[t * 2 + 1];
  const ushort4 a0 = *(const ushort4*)&P[((size_t)0 * NSLOT + s0) * C_DIM + c];
  const ushort4 a1 = *(const ushort4*)&P[((size_t)1 * NSLOT + s0) * C_DIM + c];
  const ushort4 b0 = *(const ushort4*)&P[((size_t)0 * NSLOT + s1) * C_DIM + c];
  const ushort4 b1 = *(const ushort4*)&P[((size_t)1 * NSLOT + s1) * C_DIM + c];
  float4 o = *(float4*)&out[(size_t)t * C_DIM + c];
  o.x += w0 * (bf2f(a0.x) + bf2f(a1.x)) + w1 * (bf2f(b0.x) + bf2f(b1.x));
  o.y += w0 * (bf2f(a0.y) + bf2f(a1.y)) + w1 * (bf2f(b0.y) + bf2f(b1.y));
  o.z += w0 * (bf2f(a0.z) + bf2f(a1.z)) + w1 * (bf2f(b0.z) + bf2f(b1.z));
  o.w += w0 * (bf2f(a0.w) + bf2f(a1.w)) + w1 * (bf2f(b0.w) + bf2f(b1.w));
  *(float4*)&out[(size_t)t * C_DIM + c] = o;
}

extern "C" void kernel_launch(void* const* d_in, const int* in_sizes, int n_in,
                              void* d_out, int out_size, void* d_ws, size_t ws_size,
                              hipStream_t stream) {
  const float* x            = (const float*)d_in[0];
  const float* gate_w       = (const float*)d_in[1];
  const float* lb_bias      = (const float*)d_in[2];
  const float* shared_wfc   = (const float*)d_in[3];
  const float* shared_wproj = (const float*)d_in[4];
  const float* routed_wfc   = (const float*)d_in[5];
  const float* routed_wproj = (const float*)d_in[6];
  float* out = (float*)d_out;

  char* ws = (char*)d_ws;
  unsigned short* xb     = (unsigned short*)(ws);                 // 16 MiB (dead after fcs)
  unsigned short* wfcT   = (unsigned short*)(ws + 16777216);      // 64 MiB (dead after fcs)
  unsigned short* Pb     = (unsigned short*)(ws);                 // 68 MiB partials, OVERLAYS xb+wfcT
  unsigned short* wprojT = (unsigned short*)(ws + 83886080);      // 64 MiB [8][C][H]
  unsigned short* Yg     = (unsigned short*)(ws + 150994944);     // 142.6 MiB [NSLOT][H]
  float*          cw     = (float*)(ws + 293601280);              // 224 KiB
  int*            idx    = (int*)(ws + 293830656);                // 68 KiB (NSLOT)
  int*            cnt    = (int*)(ws + 293901312);
  int*            offs   = (int*)(ws + 293901376);
  int*            cursor = (int*)(ws + 293901440);
  int*            tok2slot = (int*)(ws + 293901504);              // 64 KiB
  float*          tok2w    = (float*)(ws + 293967040);            // 64 KiB
  int*            tmap     = (int*)(ws + 294032576);              // 544 B
  int*            ntiles   = (int*)(ws + 294033152);

  cast_x_kernel<<<NTOK * C_DIM / (256 * 4), 256, 0, stream>>>(x, xb);
  init_kernel<<<(NSLOT + 255) / 256, 256, 0, stream>>>(idx, cnt, cursor);
  routing_kernel<<<NTOK / 4, 256, 0, stream>>>(x, gate_w, lb_bias, cw, cnt);
  scan_kernel<<<1, 1, 0, stream>>>(cnt, offs, tmap, ntiles);
  place_kernel<<<NTOK / 256, 256, 0, stream>>>(cw, offs, cursor, idx, tok2slot, tok2w);

  // all-expert weight transposes (e=0 shared, e=1..7 routed)
  transpose_cast_all<<<dim3(H_DIM / 32, C_DIM / 32, 8), dim3(32, 8), 0, stream>>>(
      shared_wfc, routed_wfc, wfcT, C_DIM, H_DIM);
  transpose_cast_all<<<dim3(C_DIM / 32, H_DIM / 32, 8), dim3(32, 8), 0, stream>>>(
      shared_wproj, routed_wproj, wprojT, H_DIM, C_DIM);

  // shared expert (dense): fc -> Yg[0:8192), proj -> out (direct fp32 store)
  gemm_fc<false><<<dim3(H_DIM / 128, NTOK / 128), 256, 0, stream>>>(
      xb, wfcT, Yg, idx, offs, tmap, ntiles);
  gemm_proj_shared<<<dim3(C_DIM / 128, NTOK / 128), 256, 0, stream>>>(Yg, wprojT, out);

  // routed experts (gathered top-2): grouped-XCD tile grids
  gemm_fc<true><<<dim3(H_DIM / 128, MAXT), 256, 0, stream>>>(
      xb, wfcT, Yg, idx, offs, tmap, ntiles);
  gemm_proj_routed<<<dim3(C_DIM / 128, MAXT, 2), 256, 0, stream>>>(
      Yg, wprojT, Pb, offs, tmap, ntiles);

  // out[t] += w0*(P0+P1)[slot0] + w1*(P0+P1)[slot1]
  combine_kernel<<<NTOK, 256, 0, stream>>>(Pb, tok2slot, tok2w, out);
}